// Round 13
// baseline (12148.915 us; speedup 1.0000x reference)
//
#include <hip/hip_runtime.h>
#include <hip/hip_bf16.h>

#define BB 32
#define SS 128
#define CC 128
#define HH 128
#define OO 64

typedef _Float16 f16;
typedef f16 h2 __attribute__((ext_vector_type(2)));
typedef unsigned u32x4 __attribute__((ext_vector_type(4)));   // 4 packed f16x2 pairs

__device__ __forceinline__ float sigmoidf_(float x) {
    return 1.0f / (1.0f + __expf(-x));
}
__device__ __forceinline__ float tanh_fast_(float x) {
    return 1.0f - 2.0f / (__expf(2.0f * x) + 1.0f);  // |x| small here, no overflow
}

// Pair butterfly add on the VALU pipe (DPP quad_perm xor1).
__device__ __forceinline__ float dpp_add_x1(float v) {
    int m = __builtin_amdgcn_update_dpp(0, __builtin_bit_cast(int, v),
                                        0xB1, 0xF, 0xF, true);
    return v + __builtin_bit_cast(float, m);
}

__device__ __forceinline__ h2 as_h2(unsigned u) { return __builtin_bit_cast(h2, u); }

__device__ __forceinline__ unsigned pack2f(float a, float b) {
    h2 v; v[0] = (f16)a; v[1] = (f16)b;
    return __builtin_bit_cast(unsigned, v);
}
__device__ __forceinline__ u32x4 packrow8(const float* p) {
    u32x4 r;
    r.x = pack2f(p[0], p[1]);
    r.y = pack2f(p[2], p[3]);
    r.z = pack2f(p[4], p[5]);
    r.w = pack2f(p[6], p[7]);
    return r;
}

// 8-elem f16 dot, f32 accumulate; all operands pre-packed f16x2 pairs.
__device__ __forceinline__ float dot4x2(u32x4 w, u32x4 h, float acc) {
    acc = __builtin_amdgcn_fdot2(as_h2(w.x), as_h2(h.x), acc, false);
    acc = __builtin_amdgcn_fdot2(as_h2(w.y), as_h2(h.y), acc, false);
    acc = __builtin_amdgcn_fdot2(as_h2(w.z), as_h2(h.z), acc, false);
    acc = __builtin_amdgcn_fdot2(as_h2(w.w), as_h2(h.w), acc, false);
    return acc;
}

// ROUND-13 STRUCTURE: one workgroup per BATCH; waves 0-3 run the FORWARD
// chain, waves 4-7 the BACKWARD chain (disjoint wave-sets, shared xs).
// R12 (1 wave/SIMD) measured 1055 cyc/step = ~200 issue + ~800 EXPOSED
// latency (ds round-trip, dot/trans dep chains, barrier) with no TLP.
// A second chain in OTHER WAVES gives each SIMD 2 waves with independent
// register state: chain B issues in chain A's stall shadows. R11's failure
// (both chains in one THREAD) kept issue serial and broke residency; this
// keeps the proven R12 per-thread layout (j = tc>>1, half = tc&1, 96 pinned
// weight VGPRs, VGPR_Count 132 resident).
// LDS stays inflated >80KB -> 1 block/CU -> 256-VGPR budget (R8 mechanism).
// h halves at f16-offset half*72 -> conflict-free b128 broadcasts.
// One shared barrier/step keeps the two symmetric chains in phase.
__global__
__attribute__((amdgpu_flat_work_group_size(512, 512), amdgpu_waves_per_eu(2, 2)))
void gru_chain_kernel(
    const float* __restrict__ x,       // (B,S,C)
    const float* __restrict__ h_prev,  // (2,B,H)
    const float* __restrict__ Wih_f, const float* __restrict__ Whh_f,
    const float* __restrict__ bih_f, const float* __restrict__ bhh_f,
    const float* __restrict__ Wih_b, const float* __restrict__ Whh_b,
    const float* __restrict__ bih_b, const float* __restrict__ bhh_b,
    float* __restrict__ hsnap)         // (2, C, B, H) column-end snapshots
{
    const int b    = blockIdx.x;       // batch 0..31
    const int t    = threadIdx.x;      // 0..511
    const int d    = t >> 8;           // chain: 0 = forward (waves 0-3),
                                       //        1 = backward (waves 4-7)
    const int tc   = t & 255;          // thread id within the chain
    const int j    = tc >> 1;          // hidden index 0..127
    const int half = tc & 1;           // which 64-elem half of the dot

    const float* __restrict__ Wih = d ? Wih_b : Wih_f;
    const float* __restrict__ Whh = d ? Whh_b : Whh_f;
    const float* __restrict__ bih = d ? bih_b : bih_f;
    const float* __restrict__ bhh = d ? bhh_b : bhh_f;

    // xs padded: total LDS > 80KB -> 1 block/CU -> 256-VGPR budget.
    __shared__ float xs[SS * CC + 4608];
    __shared__ __align__(16) f16 hbuf[2][2][160];  // [chain][buf][slot]

    // stage x[b] ONCE for both chains (16384 floats), coalesced float4
    {
        const float4* xb4 = reinterpret_cast<const float4*>(x + (size_t)b * SS * CC);
        float4* xs4 = reinterpret_cast<float4*>(xs);
        #pragma unroll
        for (int i = 0; i < 8; ++i) xs4[t + i * 512] = xb4[t + i * 512];
    }

    // 24 NAMED u32x4 (96 VGPRs) of packed f16 pairs: rows j, j+128, j+256,
    // this thread's 64-element half.
    const float* rowr = Whh + (j          ) * HH + half * 64;
    const float* rowz = Whh + (j +     HH ) * HH + half * 64;
    const float* rown = Whh + (j + 2 * HH ) * HH + half * 64;
    u32x4 wr0 = packrow8(rowr +  0), wr1 = packrow8(rowr +  8),
          wr2 = packrow8(rowr + 16), wr3 = packrow8(rowr + 24),
          wr4 = packrow8(rowr + 32), wr5 = packrow8(rowr + 40),
          wr6 = packrow8(rowr + 48), wr7 = packrow8(rowr + 56);
    u32x4 wz0 = packrow8(rowz +  0), wz1 = packrow8(rowz +  8),
          wz2 = packrow8(rowz + 16), wz3 = packrow8(rowz + 24),
          wz4 = packrow8(rowz + 32), wz5 = packrow8(rowz + 40),
          wz6 = packrow8(rowz + 48), wz7 = packrow8(rowz + 56);
    u32x4 wn0 = packrow8(rown +  0), wn1 = packrow8(rown +  8),
          wn2 = packrow8(rown + 16), wn3 = packrow8(rown + 24),
          wn4 = packrow8(rown + 32), wn5 = packrow8(rown + 40),
          wn6 = packrow8(rown + 48), wn7 = packrow8(rown + 56);
    asm volatile("" : "+v"(wr0), "+v"(wr1), "+v"(wr2), "+v"(wr3),
                      "+v"(wr4), "+v"(wr5), "+v"(wr6), "+v"(wr7),
                      "+v"(wz0), "+v"(wz1), "+v"(wz2), "+v"(wz3));
    asm volatile("" : "+v"(wz4), "+v"(wz5), "+v"(wz6), "+v"(wz7),
                      "+v"(wn0), "+v"(wn1), "+v"(wn2), "+v"(wn3),
                      "+v"(wn4), "+v"(wn5), "+v"(wn6), "+v"(wn7));

    const float wih_r = Wih[j];
    const float wih_z = Wih[j + HH];
    const float wih_n = Wih[j + 2 * HH];
    const float brz_r2 = 0.5f * (bih[j]      + bhh[j]);      // pair-seeded bias
    const float brz_z2 = 0.5f * (bih[j + HH] + bhh[j + HH]);
    const float bhh_n2 = 0.5f * bhh[j + 2 * HH];
    const float bih_n  = bih[j + 2 * HH];

    float hp = h_prev[(d * BB + b) * HH + j];    // f32 carry (both lanes)
    const int hwr = ((j >> 6) * 72) + (j & 63);  // skewed write slot (f16 idx)
    if (half == 0) hbuf[d][0][hwr] = (f16)hp;
    __syncthreads();

    // One GRU step: read h (f16 pairs) from hbuf[d][SRC], write to hbuf[d][DST].
#define GSTEP(SRC, DST, TSS)                                                   \
    {                                                                          \
        const int tt = d ? (SS - 1 - (TSS)) : (TSS);                           \
        const float xv = xs[tt * CC + c];        /* uniform broadcast read */  \
        const u32x4* hb =                                                      \
            reinterpret_cast<const u32x4*>(&hbuf[d][SRC][half * 72]);          \
        const u32x4 h0 = hb[0], h1 = hb[1], h2 = hb[2], h3 = hb[3],            \
                    h4 = hb[4], h5 = hb[5], h6 = hb[6], h7 = hb[7];            \
        float r0 = dot4x2(wr0, h0, brz_r2), r1 = dot4x2(wr1, h1, 0.f),         \
              r2 = dot4x2(wr2, h2, 0.f),    r3 = dot4x2(wr3, h3, 0.f);         \
        float z0 = dot4x2(wz0, h0, brz_z2), z1 = dot4x2(wz1, h1, 0.f),         \
              z2 = dot4x2(wz2, h2, 0.f),    z3 = dot4x2(wz3, h3, 0.f);         \
        float n0 = dot4x2(wn0, h0, bhh_n2), n1 = dot4x2(wn1, h1, 0.f),         \
              n2 = dot4x2(wn2, h2, 0.f),    n3 = dot4x2(wn3, h3, 0.f);         \
        r0 = dot4x2(wr4, h4, r0); r1 = dot4x2(wr5, h5, r1);                    \
        r2 = dot4x2(wr6, h6, r2); r3 = dot4x2(wr7, h7, r3);                    \
        z0 = dot4x2(wz4, h4, z0); z1 = dot4x2(wz5, h5, z1);                    \
        z2 = dot4x2(wz6, h6, z2); z3 = dot4x2(wz7, h7, z3);                    \
        n0 = dot4x2(wn4, h4, n0); n1 = dot4x2(wn5, h5, n1);                    \
        n2 = dot4x2(wn6, h6, n2); n3 = dot4x2(wn7, h7, n3);                    \
        float sr = (r0 + r1) + (r2 + r3);                                      \
        float sz = (z0 + z1) + (z2 + z3);                                      \
        float sn = (n0 + n1) + (n2 + n3);                                      \
        sr = dpp_add_x1(sr);                    /* one reduce stage */         \
        sz = dpp_add_x1(sz);                                                   \
        sn = dpp_add_x1(sn);                                                   \
        const float r = sigmoidf_(fmaf(xv, wih_r, sr));                        \
        const float z = sigmoidf_(fmaf(xv, wih_z, sz));                        \
        const float gi_n = fmaf(xv, wih_n, bih_n);                             \
        const float n = tanh_fast_(fmaf(r, sn, gi_n));                         \
        hp = fmaf(z, hp - n, n);                /* (1-z)*n + z*h  (f32) */     \
        if (half == 0) hbuf[d][DST][hwr] = (f16)hp;                            \
        __syncthreads();                                                       \
    }

    for (int c = 0; c < CC; ++c) {
        for (int ts = 0; ts < SS; ts += 2) {
            GSTEP(0, 1, ts)        // h: buf0 -> buf1
            GSTEP(1, 0, ts + 1)    // h: buf1 -> buf0
        }
        if (half == 0) {
            hsnap[(((size_t)d * CC + c) * BB + b) * HH + j] = hp;
        }
    }
#undef GSTEP
}

// One block (= one wave of 64 threads) per (c,b): FC + ReLU + softmax over O=64.
__global__ __launch_bounds__(64) void fc_softmax_kernel(
    const float* __restrict__ hsnap,   // (2, C, B, H)
    const float* __restrict__ W_fc,    // (O, 2H)
    const float* __restrict__ b_fc,    // (O,)
    float* __restrict__ out)           // (B, C, O)
{
    const int cb = blockIdx.x;         // c * B + b
    const int c  = cb >> 5;
    const int b  = cb & 31;
    const int o  = threadIdx.x;        // 0..63

    __shared__ float feat[2 * HH];     // [hf, hb]
    #pragma unroll
    for (int i = 0; i < 4; ++i) {
        const int idx = i * 64 + o;            // 0..255
        const int dd  = idx >> 7;              // 0: hf, 1: hb
        const int jj  = idx & (HH - 1);
        feat[idx] = hsnap[(((size_t)dd * CC + c) * BB + b) * HH + jj];
    }
    __syncthreads();

    float acc = 0.f;
    const float4* wrow = reinterpret_cast<const float4*>(W_fc + o * 2 * HH);
    const float4* f4   = reinterpret_cast<const float4*>(feat);
    #pragma unroll
    for (int k = 0; k < 64; ++k) {
        const float4 wv = wrow[k];
        const float4 fv = f4[k];
        acc = fmaf(wv.x, fv.x, acc);
        acc = fmaf(wv.y, fv.y, acc);
        acc = fmaf(wv.z, fv.z, acc);
        acc = fmaf(wv.w, fv.w, acc);
    }
    float v = fmaxf(acc + b_fc[o], 0.0f);

    float m = v;
    #pragma unroll
    for (int off = 32; off; off >>= 1) m = fmaxf(m, __shfl_xor(m, off));
    const float e = __expf(v - m);
    float ssum = e;
    #pragma unroll
    for (int off = 32; off; off >>= 1) ssum += __shfl_xor(ssum, off);

    out[((size_t)b * CC + c) * OO + o] = e / ssum;
}

extern "C" void kernel_launch(void* const* d_in, const int* in_sizes, int n_in,
                              void* d_out, int out_size, void* d_ws, size_t ws_size,
                              hipStream_t stream) {
    const float* x      = (const float*)d_in[0];
    const float* h_prev = (const float*)d_in[1];
    const float* Wih_f  = (const float*)d_in[2];
    const float* Whh_f  = (const float*)d_in[3];
    const float* bih_f  = (const float*)d_in[4];
    const float* bhh_f  = (const float*)d_in[5];
    const float* Wih_b  = (const float*)d_in[6];
    const float* Whh_b  = (const float*)d_in[7];
    const float* bih_b  = (const float*)d_in[8];
    const float* bhh_b  = (const float*)d_in[9];
    const float* W_fc   = (const float*)d_in[10];
    const float* b_fc   = (const float*)d_in[11];
    float* out   = (float*)d_out;
    float* hsnap = (float*)d_ws;   // 2*C*B*H*4 = 4 MiB of scratch

    gru_chain_kernel<<<BB, 512, 0, stream>>>(x, h_prev, Wih_f, Whh_f, bih_f, bhh_f,
                                             Wih_b, Whh_b, bih_b, bhh_b, hsnap);
    fc_softmax_kernel<<<CC * BB, 64, 0, stream>>>(hsnap, W_fc, b_fc, out);
}